// Round 1
// baseline (947.662 us; speedup 1.0000x reference)
//
#include <hip/hip_runtime.h>
#include <hip/hip_bf16.h>

typedef unsigned short u16;
typedef unsigned int u32;
typedef __attribute__((ext_vector_type(8))) short short8;
typedef __attribute__((ext_vector_type(4))) float f32x4;

#define BM 128
#define BN 128
#define BK 32
#define LDK 40  // padded LDS k-stride in shorts (80 B) -> 2-way-max bank aliasing

static __device__ __forceinline__ u16 f2bf(float f) {
  union { __hip_bfloat16 b; u16 u; } c;
  c.b = __float2bfloat16(f);
  return c.u;
}
static __device__ __forceinline__ float bf2f(u16 u) {
  return __uint_as_float(((u32)u) << 16);
}

__global__ __launch_bounds__(256, 2)
void bitnet_gemm_kernel(const float* __restrict__ X, const float* __restrict__ W,
                        const float* __restrict__ Bias, float* __restrict__ C,
                        int M, int N, int K) {
  __shared__ u16 AsH[BM][LDK];
  __shared__ u16 AsL[BM][LDK];
  __shared__ u16 Bs[BN][LDK];

  // XCD-aware bijective swizzle (grid % 8 == 0 here: 64*32 = 2048)
  const int nwg = gridDim.x;
  const int bid = blockIdx.x;
  const int swz = ((nwg & 7) == 0) ? ((bid & 7) * (nwg >> 3) + (bid >> 3)) : bid;
  const int nbn = N / BN;
  const int brow = swz / nbn;
  const int bcol = swz % nbn;

  const int tid = threadIdx.x;
  const int lane = tid & 63;
  const int wid = tid >> 6;
  const int wr = wid >> 1;  // wave row 0..1 (64-row slab)
  const int wc = wid & 1;   // wave col 0..1 (64-col slab)

  // staging decomposition: thread -> (row 0..63, 8-float chunk of BK)
  const int srow = tid >> 2;
  const int skc = (tid & 3) * 8;

  const float* Ab = X + (size_t)brow * BM * K;
  const float* Bb = W + (size_t)bcol * BN * K;

  f32x4 acc[4][4];
#pragma unroll
  for (int m = 0; m < 4; ++m)
#pragma unroll
    for (int n = 0; n < 4; ++n)
#pragma unroll
      for (int j = 0; j < 4; ++j) acc[m][n][j] = 0.f;

  const int r0 = lane & 15;
  const int k0 = (lane >> 4) * 8;

  for (int kt = 0; kt < K; kt += BK) {
    __syncthreads();
    // ---- stage A tile as hi/lo bf16 split (fp32-accurate two-term) ----
#pragma unroll
    for (int p = 0; p < 2; ++p) {
      const int row = p * 64 + srow;
      const float* src = Ab + (size_t)row * K + kt + skc;
      const float4 v0 = *(const float4*)(src);
      const float4 v1 = *(const float4*)(src + 4);
      const float v[8] = {v0.x, v0.y, v0.z, v0.w, v1.x, v1.y, v1.z, v1.w};
      short8 ph, pl;
#pragma unroll
      for (int j = 0; j < 8; ++j) {
        const u16 h = f2bf(v[j]);
        const float rem = v[j] - bf2f(h);
        ph[j] = (short)h;
        pl[j] = (short)f2bf(rem);
      }
      *(short8*)&AsH[row][skc] = ph;
      *(short8*)&AsL[row][skc] = pl;
    }
    // ---- stage B tile as sign(w) in bf16 ({-1,0,+1} exact) ----
#pragma unroll
    for (int p = 0; p < 2; ++p) {
      const int row = p * 64 + srow;
      const float* src = Bb + (size_t)row * K + kt + skc;
      const float4 v0 = *(const float4*)(src);
      const float4 v1 = *(const float4*)(src + 4);
      const float v[8] = {v0.x, v0.y, v0.z, v0.w, v1.x, v1.y, v1.z, v1.w};
      short8 pq;
#pragma unroll
      for (int j = 0; j < 8; ++j) {
        const u32 b = __float_as_uint(v[j]);
        // sign(0) = 0 (covers +-0); else +-1.0bf16 = 0x3F80 | signbit
        const u16 q = ((b << 1) == 0) ? (u16)0
                                      : (u16)(0x3F80u | ((b >> 16) & 0x8000u));
        pq[j] = (short)q;
      }
      *(short8*)&Bs[row][skc] = pq;
    }
    __syncthreads();

    // ---- fragment loads (ds_read_b128) + MFMA ----
    short8 ah[4], al[4], bq[4];
#pragma unroll
    for (int m = 0; m < 4; ++m) {
      ah[m] = *(const short8*)&AsH[wr * 64 + m * 16 + r0][k0];
      al[m] = *(const short8*)&AsL[wr * 64 + m * 16 + r0][k0];
    }
#pragma unroll
    for (int n = 0; n < 4; ++n)
      bq[n] = *(const short8*)&Bs[wc * 64 + n * 16 + r0][k0];

#pragma unroll
    for (int m = 0; m < 4; ++m)
#pragma unroll
      for (int n = 0; n < 4; ++n) {
        acc[m][n] = __builtin_amdgcn_mfma_f32_16x16x32_bf16(ah[m], bq[n], acc[m][n], 0, 0, 0);
        acc[m][n] = __builtin_amdgcn_mfma_f32_16x16x32_bf16(al[m], bq[n], acc[m][n], 0, 0, 0);
      }
  }

  // ---- epilogue: bias + store (C/D: col = lane&15, row = (lane>>4)*4 + reg) ----
  const int rbase = (lane >> 4) * 4;
  const int crow0 = brow * BM + wr * 64;
  const int ccol0 = bcol * BN + wc * 64;
#pragma unroll
  for (int n = 0; n < 4; ++n) {
    const int col = ccol0 + n * 16 + r0;
    const float bb = Bias[col];
#pragma unroll
    for (int m = 0; m < 4; ++m) {
      const int row = crow0 + m * 16 + rbase;
#pragma unroll
      for (int j = 0; j < 4; ++j) {
        C[(size_t)(row + j) * N + col] = acc[m][n][j] + bb;
      }
    }
  }
}

extern "C" void kernel_launch(void* const* d_in, const int* in_sizes, int n_in,
                              void* d_out, int out_size, void* d_ws, size_t ws_size,
                              hipStream_t stream) {
  const float* X = (const float*)d_in[0];     // [B*S, K] fp32
  const float* W = (const float*)d_in[1];     // [N, K] fp32
  const float* Bias = (const float*)d_in[2];  // [N] fp32
  float* C = (float*)d_out;                   // [B*S, N] fp32

  const int N = in_sizes[2];       // 4096
  const int K = in_sizes[1] / N;   // 4096
  const int M = in_sizes[0] / K;   // 8192

  const int grid = (M / BM) * (N / BN);  // 64 * 32 = 2048
  bitnet_gemm_kernel<<<grid, 256, 0, stream>>>(X, W, Bias, C, M, N, K);
}

// Round 2
// 669.663 us; speedup vs baseline: 1.4151x; 1.4151x over previous
//
#include <hip/hip_runtime.h>
#include <hip/hip_bf16.h>
#include <stdint.h>

typedef unsigned short u16;
typedef unsigned int u32;
typedef __attribute__((ext_vector_type(8))) short short8;
typedef __attribute__((ext_vector_type(4))) float f32x4;

static __device__ __forceinline__ u16 f2bf(float f) {
  union { __hip_bfloat16 b; u16 u; } c;
  c.b = __float2bfloat16(f);
  return c.u;
}
static __device__ __forceinline__ float bf2f(u16 u) {
  return __uint_as_float(((u32)u) << 16);
}

// ---------------- prep kernels ----------------
// X fp32 [M][4096] -> Ahl bf16 [M][8192]: cols 0..4095 = hi, 4096..8191 = lo
__global__ __launch_bounds__(256) void prep_x(const float* __restrict__ X,
                                              u16* __restrict__ Ahl) {
  const u32 t = blockIdx.x * 256 + threadIdx.x;
  const size_t i = (size_t)t * 8;
  const float4 v0 = *(const float4*)(X + i);
  const float4 v1 = *(const float4*)(X + i + 4);
  const float v[8] = {v0.x, v0.y, v0.z, v0.w, v1.x, v1.y, v1.z, v1.w};
  short8 h8, l8;
#pragma unroll
  for (int j = 0; j < 8; ++j) {
    const u16 h = f2bf(v[j]);
    h8[j] = (short)h;
    l8[j] = (short)f2bf(v[j] - bf2f(h));
  }
  const u32 m = t >> 9;           // (t*8)/4096
  const u32 k = (t & 511) * 8;
  u16* p = Ahl + ((size_t)m << 13) + k;
  *(short8*)p = h8;
  *(short8*)(p + 4096) = l8;
}

// W fp32 [N][4096] -> Qw bf16 sign {-1,0,+1}
__global__ __launch_bounds__(256) void prep_w(const float* __restrict__ W,
                                              u16* __restrict__ Qw) {
  const u32 t = blockIdx.x * 256 + threadIdx.x;
  const size_t i = (size_t)t * 8;
  const float4 v0 = *(const float4*)(W + i);
  const float4 v1 = *(const float4*)(W + i + 4);
  const float v[8] = {v0.x, v0.y, v0.z, v0.w, v1.x, v1.y, v1.z, v1.w};
  short8 q8;
#pragma unroll
  for (int j = 0; j < 8; ++j) {
    const u32 b = __float_as_uint(v[j]);
    q8[j] = ((b << 1) == 0) ? (short)0
                            : (short)(u16)(0x3F80u | ((b >> 16) & 0x8000u));
  }
  *(short8*)(Qw + i) = q8;
}

// ---------------- 256x256 8-phase GEMM ----------------
#define LGKM0 asm volatile("s_waitcnt lgkmcnt(0)" ::: "memory")
#define VMCNT(n) asm volatile("s_waitcnt vmcnt(" #n ")" ::: "memory")
#define CFENCE asm volatile("" ::: "memory")
#define BAR do { __builtin_amdgcn_s_barrier(); CFENCE; } while (0)

static __device__ __forceinline__ void gload16(const void* g, void* l) {
  __builtin_amdgcn_global_load_lds(
      (const __attribute__((address_space(1))) u32*)g,
      (__attribute__((address_space(3))) u32*)l, 16, 0, 0);
}

// A: Ahl bf16 [8192][8192] (row stride 16384 B); B: Qw bf16 [4096][4096]
// (row stride 8192 B, K' wraps). C fp32 [8192][4096]. K-tiles: 128 x BK=64.
__global__ __launch_bounds__(512, 2)
void gemm256(const u16* __restrict__ A, const u16* __restrict__ B,
             const float* __restrict__ Bias, float* __restrict__ C) {
  __shared__ __align__(16) unsigned char ldsc[131072];  // A:[0,64K) B:[64K,128K)

  const int tid = threadIdx.x;
  const int lane = tid & 63;
  const int wid = tid >> 6;
  const int wm = wid >> 2;   // 0..1
  const int wn = wid & 3;    // 0..3
  const int r16 = lane & 15;
  const int khalf = lane >> 4;  // 0..3

  // XCD-bijective swizzle (512 blocks, 512%8==0)
  const int bid = blockIdx.x;
  const int swz = (bid & 7) * 64 + (bid >> 3);
  const int brow = swz >> 4;   // 0..31
  const int bcol = swz & 15;   // 0..15

  // ---- staging addresses: linear LDS dest + inverse-swizzled global src ----
  const u32 Lcol = (u32)(((tid & 7) ^ ((tid >> 3) & 7)) * 16);
  const char* Ag = (const char*)A;
  const char* Bg = (const char*)B;
  const u32 a_g0 = (u32)(brow * 256 + (tid >> 3)) * 16384u + Lcol;
  const u32 b_g0 = (u32)(bcol * 256 + (tid >> 3)) * 8192u + Lcol;
  char* const lc = (char*)ldsc;
  const u32 l_t = (u32)tid * 16u;

  // ---- ds-read offsets (swizzled) ----
  const u32 col0 = (u32)(((khalf << 4) ^ ((r16 & 7) << 4)));
  const u32 arow0 = (u32)(wm * 64 + r16) * 128u;
  const u32 brow0 = (u32)(wn * 64 + r16) * 128u + 65536u;

  f32x4 acc[8][4];
#pragma unroll
  for (int m = 0; m < 8; ++m)
#pragma unroll
    for (int n = 0; n < 4; ++n)
#pragma unroll
      for (int j = 0; j < 4; ++j) acc[m][n][j] = 0.f;
  short8 bq[4][2];

#define AOFF(P, MF, KK) ((u32)((P)*32768) + arow0 + \
    (u32)((((MF) >> 2) * 16384) + (((MF) & 3) * 2048)) + (col0 ^ ((KK) << 6)))
#define BOFF(P, NF, KK) (brow0 + (u32)((P)*32768) + (u32)((NF)*2048) + (col0 ^ ((KK) << 6)))
#define RD(off) (*(const short8*)(lc + (off)))

#define STAGE_A(TP, H, PB) do { \
    const char* g_ = Ag + a_g0 + (u32)((H)*128*16384) + (u32)(TP)*128u; \
    char* l_ = lc + (u32)((PB)*32768 + (H)*16384) + l_t; \
    gload16(g_, l_); gload16(g_ + 64*16384, l_ + 8192); } while (0)

#define STAGE_B(TP, H, PB) do { \
    const char* g_ = Bg + b_g0 + (u32)((H)*128*8192) + (u32)(((TP)&63))*128u; \
    char* l_ = lc + 65536u + (u32)((PB)*32768 + (H)*16384) + l_t; \
    gload16(g_, l_); gload16(g_ + 64*8192, l_ + 8192); } while (0)

#define MM4(MF, A0, A1) do { \
    _Pragma("unroll") for (int nf_ = 0; nf_ < 4; ++nf_) { \
      acc[MF][nf_] = __builtin_amdgcn_mfma_f32_16x16x32_bf16(A0, bq[nf_][0], acc[MF][nf_], 0, 0, 0); \
      acc[MF][nf_] = __builtin_amdgcn_mfma_f32_16x16x32_bf16(A1, bq[nf_][1], acc[MF][nf_], 0, 0, 0); } } while (0)

  // phase = [stage prefetch][ds_read][BAR][lgkmcnt(0)+sched_barrier][16 MFMA][(vmcnt)][BAR]
#define PHASE0(P, S) do { \
    S; \
    const short8 a00 = RD(AOFF(P, 0, 0)), a01 = RD(AOFF(P, 0, 1)); \
    const short8 a10 = RD(AOFF(P, 1, 0)), a11 = RD(AOFF(P, 1, 1)); \
    _Pragma("unroll") for (int nf_ = 0; nf_ < 4; ++nf_) { \
      bq[nf_][0] = RD(BOFF(P, nf_, 0)); bq[nf_][1] = RD(BOFF(P, nf_, 1)); } \
    BAR; LGKM0; __builtin_amdgcn_sched_barrier(0); \
    __builtin_amdgcn_s_setprio(1); MM4(0, a00, a01); MM4(1, a10, a11); \
    __builtin_amdgcn_s_setprio(0); BAR; } while (0)

#define PHASEX(P, MF0, S, TW) do { \
    S; \
    const short8 a00 = RD(AOFF(P, MF0, 0)), a01 = RD(AOFF(P, MF0, 1)); \
    const short8 a10 = RD(AOFF(P, (MF0)+1, 0)), a11 = RD(AOFF(P, (MF0)+1, 1)); \
    BAR; LGKM0; __builtin_amdgcn_sched_barrier(0); \
    __builtin_amdgcn_s_setprio(1); MM4(MF0, a00, a01); MM4((MF0)+1, a10, a11); \
    __builtin_amdgcn_s_setprio(0); TW; BAR; } while (0)

  // prologue: tile0 fully (8 loads), tile1 A-h0 + B (6 loads); allow tile1 in flight
  STAGE_A(0, 0, 0); STAGE_A(0, 1, 0); STAGE_B(0, 0, 0); STAGE_B(0, 1, 0);
  STAGE_A(1, 0, 1); STAGE_B(1, 0, 1); STAGE_B(1, 1, 1);
  VMCNT(6); BAR;

  int T = 0;
#pragma unroll 1
  for (int it = 0; it < 63; ++it) {
    // tile T (parity 0): mf 0-1 / 2-3 read A-half0; 4-5 / 6-7 read A-half1
    PHASE0(0, STAGE_A(T + 1, 1, 1));
    PHASEX(0, 2, STAGE_B(T + 2, 0, 0), );
    PHASEX(0, 4, STAGE_B(T + 2, 1, 0), );
    PHASEX(0, 6, STAGE_A(T + 2, 0, 0), VMCNT(6));
    // tile T+1 (parity 1)
    PHASE0(1, STAGE_A(T + 2, 1, 0));
    PHASEX(1, 2, STAGE_B(T + 3, 0, 1), );
    PHASEX(1, 4, STAGE_B(T + 3, 1, 1), );
    PHASEX(1, 6, STAGE_A(T + 3, 0, 1), VMCNT(6));
    T += 2;
  }
  // tail: tiles 126, 127
  PHASE0(0, STAGE_A(127, 1, 1));
  PHASEX(0, 2, , );
  PHASEX(0, 4, , );
  PHASEX(0, 6, , VMCNT(0));
  PHASE0(1, );
  PHASEX(1, 2, , );
  PHASEX(1, 4, , );
  PHASEX(1, 6, , );

  // ---- epilogue: bias + store. C/D: col = lane&15, row = khalf*4 + j ----
  const int ccol0 = bcol * 256 + wn * 64 + r16;
  float bb[4];
#pragma unroll
  for (int nf = 0; nf < 4; ++nf) bb[nf] = Bias[ccol0 + nf * 16];
  const int crow_base = brow * 256 + wm * 64 + khalf * 4;
#pragma unroll
  for (int mf = 0; mf < 8; ++mf) {
    const int row = crow_base + (mf >> 2) * 128 + (mf & 3) * 16;
#pragma unroll
    for (int nf = 0; nf < 4; ++nf) {
      const int col = ccol0 + nf * 16;
#pragma unroll
      for (int j = 0; j < 4; ++j)
        C[(size_t)(row + j) * 4096 + col] = acc[mf][nf][j] + bb[nf];
    }
  }
#undef AOFF
#undef BOFF
#undef RD
#undef STAGE_A
#undef STAGE_B
#undef MM4
#undef PHASE0
#undef PHASEX
}

// ---------------- fallback (round-1 kernel, any shape) ----------------
#define BM 128
#define BN 128
#define BK 32
#define LDKP 40

__global__ __launch_bounds__(256, 2)
void bitnet_gemm_fallback(const float* __restrict__ X, const float* __restrict__ W,
                          const float* __restrict__ Bias, float* __restrict__ C,
                          int M, int N, int K) {
  __shared__ u16 AsH[BM][LDKP];
  __shared__ u16 AsL[BM][LDKP];
  __shared__ u16 Bs[BN][LDKP];
  const int nwg = gridDim.x;
  const int bid = blockIdx.x;
  const int swz = ((nwg & 7) == 0) ? ((bid & 7) * (nwg >> 3) + (bid >> 3)) : bid;
  const int nbn = N / BN;
  const int brow = swz / nbn;
  const int bcol = swz % nbn;
  const int tid = threadIdx.x;
  const int lane = tid & 63;
  const int wid = tid >> 6;
  const int wr = wid >> 1;
  const int wc = wid & 1;
  const int srow = tid >> 2;
  const int skc = (tid & 3) * 8;
  const float* Ab = X + (size_t)brow * BM * K;
  const float* Bb = W + (size_t)bcol * BN * K;
  f32x4 acc[4][4];
#pragma unroll
  for (int m = 0; m < 4; ++m)
#pragma unroll
    for (int n = 0; n < 4; ++n)
#pragma unroll
      for (int j = 0; j < 4; ++j) acc[m][n][j] = 0.f;
  const int r0 = lane & 15;
  const int k0 = (lane >> 4) * 8;
  for (int kt = 0; kt < K; kt += BK) {
    __syncthreads();
#pragma unroll
    for (int p = 0; p < 2; ++p) {
      const int row = p * 64 + srow;
      const float* src = Ab + (size_t)row * K + kt + skc;
      const float4 v0 = *(const float4*)(src);
      const float4 v1 = *(const float4*)(src + 4);
      const float v[8] = {v0.x, v0.y, v0.z, v0.w, v1.x, v1.y, v1.z, v1.w};
      short8 ph, pl;
#pragma unroll
      for (int j = 0; j < 8; ++j) {
        const u16 h = f2bf(v[j]);
        const float rem = v[j] - bf2f(h);
        ph[j] = (short)h;
        pl[j] = (short)f2bf(rem);
      }
      *(short8*)&AsH[row][skc] = ph;
      *(short8*)&AsL[row][skc] = pl;
    }
#pragma unroll
    for (int p = 0; p < 2; ++p) {
      const int row = p * 64 + srow;
      const float* src = Bb + (size_t)row * K + kt + skc;
      const float4 v0 = *(const float4*)(src);
      const float4 v1 = *(const float4*)(src + 4);
      const float v[8] = {v0.x, v0.y, v0.z, v0.w, v1.x, v1.y, v1.z, v1.w};
      short8 pq;
#pragma unroll
      for (int j = 0; j < 8; ++j) {
        const u32 b = __float_as_uint(v[j]);
        const u16 q = ((b << 1) == 0) ? (u16)0 : (u16)(0x3F80u | ((b >> 16) & 0x8000u));
        pq[j] = (short)q;
      }
      *(short8*)&Bs[row][skc] = pq;
    }
    __syncthreads();
    short8 ah[4], al[4], bqf[4];
#pragma unroll
    for (int m = 0; m < 4; ++m) {
      ah[m] = *(const short8*)&AsH[wr * 64 + m * 16 + r0][k0];
      al[m] = *(const short8*)&AsL[wr * 64 + m * 16 + r0][k0];
    }
#pragma unroll
    for (int n = 0; n < 4; ++n)
      bqf[n] = *(const short8*)&Bs[wc * 64 + n * 16 + r0][k0];
#pragma unroll
    for (int m = 0; m < 4; ++m)
#pragma unroll
      for (int n = 0; n < 4; ++n) {
        acc[m][n] = __builtin_amdgcn_mfma_f32_16x16x32_bf16(ah[m], bqf[n], acc[m][n], 0, 0, 0);
        acc[m][n] = __builtin_amdgcn_mfma_f32_16x16x32_bf16(al[m], bqf[n], acc[m][n], 0, 0, 0);
      }
  }
  const int rbase = (lane >> 4) * 4;
  const int crow0 = brow * BM + wr * 64;
  const int ccol0 = bcol * BN + wc * 64;
#pragma unroll
  for (int n = 0; n < 4; ++n) {
    const int col = ccol0 + n * 16 + r0;
    const float bbv = Bias[col];
#pragma unroll
    for (int m = 0; m < 4; ++m) {
      const int row = crow0 + m * 16 + rbase;
#pragma unroll
      for (int j = 0; j < 4; ++j) {
        C[(size_t)(row + j) * N + col] = acc[m][n][j] + bbv;
      }
    }
  }
}

extern "C" void kernel_launch(void* const* d_in, const int* in_sizes, int n_in,
                              void* d_out, int out_size, void* d_ws, size_t ws_size,
                              hipStream_t stream) {
  const float* X = (const float*)d_in[0];     // [M, K] fp32
  const float* W = (const float*)d_in[1];     // [N, K] fp32
  const float* Bias = (const float*)d_in[2];  // [N] fp32
  float* C = (float*)d_out;                   // [M, N] fp32

  const int N = in_sizes[2];
  const int K = in_sizes[1] / N;
  const int M = in_sizes[0] / K;

  const size_t ahl_bytes = (size_t)M * 2 * K * 2;  // bf16 [M][2K]
  const size_t qw_bytes = (size_t)N * K * 2;       // bf16 [N][K]

  if (M == 8192 && N == 4096 && K == 4096 && ws_size >= ahl_bytes + qw_bytes) {
    u16* Ahl = (u16*)d_ws;
    u16* Qw = (u16*)((char*)d_ws + ahl_bytes);
    prep_x<<<(M * K) / (8 * 256), 256, 0, stream>>>(X, Ahl);
    prep_w<<<(N * K) / (8 * 256), 256, 0, stream>>>(W, Qw);
    gemm256<<<(M / 256) * (N / 256), 512, 0, stream>>>(Ahl, Qw, Bias, C);
  } else {
    bitnet_gemm_fallback<<<(M / BM) * (N / BN), 256, 0, stream>>>(X, W, Bias, C, M, N, K);
  }
}

// Round 3
// 518.742 us; speedup vs baseline: 1.8268x; 1.2909x over previous
//
#include <hip/hip_runtime.h>
#include <hip/hip_bf16.h>
#include <stdint.h>

typedef unsigned short u16;
typedef unsigned int u32;
typedef __attribute__((ext_vector_type(8))) short short8;
typedef __attribute__((ext_vector_type(4))) float f32x4;
typedef __attribute__((ext_vector_type(4))) int i32x4;

static __device__ __forceinline__ u16 f2bf(float f) {
  union { __hip_bfloat16 b; u16 u; } c;
  c.b = __float2bfloat16(f);
  return c.u;
}
static __device__ __forceinline__ float bf2f(u16 u) {
  return __uint_as_float(((u32)u) << 16);
}

// ---------------- prep kernels (i8 two-term) ----------------
// x ~= q1/16 + q2/4096, q1,q2 in i8. One float4 per thread, 4B packed stores.
__global__ __launch_bounds__(256) void prep_x_i8(const float* __restrict__ X,
                                                 char* __restrict__ A1,
                                                 char* __restrict__ A2) {
  const u32 t = blockIdx.x * 256 + threadIdx.x;
  const float4 v = ((const float4*)X)[t];
  const float vv[4] = {v.x, v.y, v.z, v.w};
  u32 p1 = 0, p2 = 0;
#pragma unroll
  for (int j = 0; j < 4; ++j) {
    float q1f = rintf(vv[j] * 16.f);
    q1f = fminf(fmaxf(q1f, -127.f), 127.f);
    const float r = vv[j] - q1f * 0.0625f;
    float q2f = rintf(r * 4096.f);
    q2f = fminf(fmaxf(q2f, -127.f), 127.f);
    p1 |= ((u32)((int)q1f & 0xFF)) << (8 * j);
    p2 |= ((u32)((int)q2f & 0xFF)) << (8 * j);
  }
  ((u32*)A1)[t] = p1;
  ((u32*)A2)[t] = p2;
}

// W fp32 -> sign in i8 {-1,0,+1}
__global__ __launch_bounds__(256) void prep_w_i8(const float* __restrict__ W,
                                                 char* __restrict__ Qw) {
  const u32 t = blockIdx.x * 256 + threadIdx.x;
  const float4 v = ((const float4*)W)[t];
  const float vv[4] = {v.x, v.y, v.z, v.w};
  u32 p = 0;
#pragma unroll
  for (int j = 0; j < 4; ++j) {
    const u32 b = __float_as_uint(vv[j]);
    const int q = ((b << 1) == 0) ? 0 : ((b >> 31) ? -1 : 1);
    p |= ((u32)(q & 0xFF)) << (8 * j);
  }
  ((u32*)Qw)[t] = p;
}

// ---------------- 256x256 8-phase i8 GEMM (one term per dispatch) ----------------
#define LGKM0 asm volatile("s_waitcnt lgkmcnt(0)" ::: "memory")
#define VMCNT(n) asm volatile("s_waitcnt vmcnt(" #n ")" ::: "memory")
#define CFENCE asm volatile("" ::: "memory")
#define BAR do { __builtin_amdgcn_s_barrier(); CFENCE; } while (0)

static __device__ __forceinline__ void gload16(const void* g, void* l) {
  __builtin_amdgcn_global_load_lds(
      (const __attribute__((address_space(1))) u32*)g,
      (__attribute__((address_space(3))) u32*)l, 16, 0, 0);
}

// A: i8 [8192][4096] (row 4096 B); B: i8 [4096][4096]. C fp32 [8192][4096].
// K-tiles: 32 x BK=128 (128 B rows -> byte-geometry identical to the verified
// round-2 bf16 kernel; bank-conflict-free XOR swizzle; vmcnt(6) schedule).
// PASS 0: C = acc/16.  PASS 1: C += acc/4096 + bias.
template <int PASS>
__global__ __launch_bounds__(512, 2)
void gemm256_i8(const char* __restrict__ A, const char* __restrict__ B,
                const float* __restrict__ Bias, float* __restrict__ C) {
  __shared__ __align__(16) unsigned char ldsc[131072];  // A:[0,64K) B:[64K,128K)

  const int tid = threadIdx.x;
  const int lane = tid & 63;
  const int wid = tid >> 6;
  const int wm = wid >> 2;     // 0..1
  const int wn = wid & 3;      // 0..3
  const int r16 = lane & 15;
  const int khalf = lane >> 4; // 0..3

  // XCD-bijective swizzle (512 blocks, 512%8==0)
  const int bid = blockIdx.x;
  const int swz = (bid & 7) * 64 + (bid >> 3);
  const int brow = swz >> 4;   // 0..31
  const int bcol = swz & 15;   // 0..15

  // staging: linear LDS dest + inverse-swizzled global src (rule 21)
  const u32 Lcol = (u32)(((tid & 7) ^ ((tid >> 3) & 7)) * 16);
  const char* Ag = (const char*)A;
  const char* Bg = (const char*)B;
  const u32 a_g0 = (u32)(brow * 256 + (tid >> 3)) * 4096u + Lcol;
  const u32 b_g0 = (u32)(bcol * 256 + (tid >> 3)) * 4096u + Lcol;
  char* const lc = (char*)ldsc;
  const u32 l_t = (u32)tid * 16u;

  // ds-read offsets (swizzled)
  const u32 col0 = (u32)(((khalf << 4) ^ ((r16 & 7) << 4)));
  const u32 arow0 = (u32)(wm * 64 + r16) * 128u;
  const u32 brow0 = (u32)(wn * 64 + r16) * 128u + 65536u;

  i32x4 acc[8][4];
#pragma unroll
  for (int m = 0; m < 8; ++m)
#pragma unroll
    for (int n = 0; n < 4; ++n)
#pragma unroll
      for (int j = 0; j < 4; ++j) acc[m][n][j] = 0;
  i32x4 bq[4][2];

#define AOFF(P, MF, KK) ((u32)((P)*32768) + arow0 + \
    (u32)((((MF) >> 2) * 16384) + (((MF) & 3) * 2048)) + (col0 ^ ((KK) << 6)))
#define BOFF(P, NF, KK) (brow0 + (u32)((P)*32768) + (u32)((NF)*2048) + (col0 ^ ((KK) << 6)))
#define RD(off) (*(const i32x4*)(lc + (off)))

#define STAGE_A(TP, H, PB) do { \
    const char* g_ = Ag + a_g0 + (u32)((H)*128*4096) + (u32)(TP)*128u; \
    char* l_ = lc + (u32)((PB)*32768 + (H)*16384) + l_t; \
    gload16(g_, l_); gload16(g_ + 64*4096, l_ + 8192); } while (0)

#define STAGE_B(TP, H, PB) do { \
    const char* g_ = Bg + b_g0 + (u32)((H)*128*4096) + (u32)(TP)*128u; \
    char* l_ = lc + 65536u + (u32)((PB)*32768 + (H)*16384) + l_t; \
    gload16(g_, l_); gload16(g_ + 64*4096, l_ + 8192); } while (0)

#define MM4(MF, A0, A1r) do { \
    _Pragma("unroll") for (int nf_ = 0; nf_ < 4; ++nf_) { \
      acc[MF][nf_] = __builtin_amdgcn_mfma_i32_16x16x64_i8(A0, bq[nf_][0], acc[MF][nf_], 0, 0, 0); \
      acc[MF][nf_] = __builtin_amdgcn_mfma_i32_16x16x64_i8(A1r, bq[nf_][1], acc[MF][nf_], 0, 0, 0); } } while (0)

#define PHASE0(P, S) do { \
    S; \
    const i32x4 a00 = RD(AOFF(P, 0, 0)), a01 = RD(AOFF(P, 0, 1)); \
    const i32x4 a10 = RD(AOFF(P, 1, 0)), a11 = RD(AOFF(P, 1, 1)); \
    _Pragma("unroll") for (int nf_ = 0; nf_ < 4; ++nf_) { \
      bq[nf_][0] = RD(BOFF(P, nf_, 0)); bq[nf_][1] = RD(BOFF(P, nf_, 1)); } \
    BAR; LGKM0; __builtin_amdgcn_sched_barrier(0); \
    __builtin_amdgcn_s_setprio(1); MM4(0, a00, a01); MM4(1, a10, a11); \
    __builtin_amdgcn_s_setprio(0); BAR; } while (0)

#define PHASEX(P, MF0, S, TW) do { \
    S; \
    const i32x4 a00 = RD(AOFF(P, MF0, 0)), a01 = RD(AOFF(P, MF0, 1)); \
    const i32x4 a10 = RD(AOFF(P, (MF0)+1, 0)), a11 = RD(AOFF(P, (MF0)+1, 1)); \
    BAR; LGKM0; __builtin_amdgcn_sched_barrier(0); \
    __builtin_amdgcn_s_setprio(1); MM4(MF0, a00, a01); MM4((MF0)+1, a10, a11); \
    __builtin_amdgcn_s_setprio(0); TW; BAR; } while (0)

  // prologue: tile0 fully (8 loads), tile1 A-h0 + B (6 loads)
  STAGE_A(0, 0, 0); STAGE_A(0, 1, 0); STAGE_B(0, 0, 0); STAGE_B(0, 1, 0);
  STAGE_A(1, 0, 1); STAGE_B(1, 0, 1); STAGE_B(1, 1, 1);
  VMCNT(6); BAR;

  int T = 0;
#pragma unroll 1
  for (int it = 0; it < 15; ++it) {
    PHASE0(0, STAGE_A(T + 1, 1, 1));
    PHASEX(0, 2, STAGE_B(T + 2, 0, 0), );
    PHASEX(0, 4, STAGE_B(T + 2, 1, 0), );
    PHASEX(0, 6, STAGE_A(T + 2, 0, 0), VMCNT(6));
    PHASE0(1, STAGE_A(T + 2, 1, 0));
    PHASEX(1, 2, STAGE_B(T + 3, 0, 1), );
    PHASEX(1, 4, STAGE_B(T + 3, 1, 1), );
    PHASEX(1, 6, STAGE_A(T + 3, 0, 1), VMCNT(6));
    T += 2;
  }
  // tail: tiles 30, 31
  PHASE0(0, STAGE_A(31, 1, 1));
  PHASEX(0, 2, , );
  PHASEX(0, 4, , );
  PHASEX(0, 6, , VMCNT(0));
  PHASE0(1, );
  PHASEX(1, 2, , );
  PHASEX(1, 4, , );
  PHASEX(1, 6, , );

  // epilogue: C/D layout col = lane&15, row = khalf*4 + j
  const int ccol0 = bcol * 256 + wn * 64 + r16;
  float bb[4];
#pragma unroll
  for (int nf = 0; nf < 4; ++nf) bb[nf] = Bias[ccol0 + nf * 16];
  const int crow_base = brow * 256 + wm * 64 + khalf * 4;
  const float scale = (PASS == 0) ? 0.0625f : (1.0f / 4096.0f);
#pragma unroll
  for (int mf = 0; mf < 8; ++mf) {
    const int row = crow_base + (mf >> 2) * 128 + (mf & 3) * 16;
#pragma unroll
    for (int nf = 0; nf < 4; ++nf) {
      const int col = ccol0 + nf * 16;
#pragma unroll
      for (int j = 0; j < 4; ++j) {
        const size_t idx = (size_t)(row + j) * 4096 + col;
        if (PASS == 0) {
          C[idx] = (float)acc[mf][nf][j] * scale;
        } else {
          C[idx] = C[idx] + (float)acc[mf][nf][j] * scale + bb[nf];
        }
      }
    }
  }
#undef AOFF
#undef BOFF
#undef RD
#undef STAGE_A
#undef STAGE_B
#undef MM4
#undef PHASE0
#undef PHASEX
}

// ---------------- fallback (round-1 kernel, any shape) ----------------
#define BM 128
#define BN 128
#define BK 32
#define LDKP 40

__global__ __launch_bounds__(256, 2)
void bitnet_gemm_fallback(const float* __restrict__ X, const float* __restrict__ W,
                          const float* __restrict__ Bias, float* __restrict__ C,
                          int M, int N, int K) {
  __shared__ u16 AsH[BM][LDKP];
  __shared__ u16 AsL[BM][LDKP];
  __shared__ u16 Bs[BN][LDKP];
  const int nwg = gridDim.x;
  const int bid = blockIdx.x;
  const int swz = ((nwg & 7) == 0) ? ((bid & 7) * (nwg >> 3) + (bid >> 3)) : bid;
  const int nbn = N / BN;
  const int brow = swz / nbn;
  const int bcol = swz % nbn;
  const int tid = threadIdx.x;
  const int lane = tid & 63;
  const int wid = tid >> 6;
  const int wr = wid >> 1;
  const int wc = wid & 1;
  const int srow = tid >> 2;
  const int skc = (tid & 3) * 8;
  const float* Ab = X + (size_t)brow * BM * K;
  const float* Bb = W + (size_t)bcol * BN * K;
  f32x4 acc[4][4];
#pragma unroll
  for (int m = 0; m < 4; ++m)
#pragma unroll
    for (int n = 0; n < 4; ++n)
#pragma unroll
      for (int j = 0; j < 4; ++j) acc[m][n][j] = 0.f;
  const int r0 = lane & 15;
  const int k0 = (lane >> 4) * 8;
  for (int kt = 0; kt < K; kt += BK) {
    __syncthreads();
#pragma unroll
    for (int p = 0; p < 2; ++p) {
      const int row = p * 64 + srow;
      const float* src = Ab + (size_t)row * K + kt + skc;
      const float4 v0 = *(const float4*)(src);
      const float4 v1 = *(const float4*)(src + 4);
      const float v[8] = {v0.x, v0.y, v0.z, v0.w, v1.x, v1.y, v1.z, v1.w};
      short8 ph, pl;
#pragma unroll
      for (int j = 0; j < 8; ++j) {
        const u16 h = f2bf(v[j]);
        const float rem = v[j] - bf2f(h);
        ph[j] = (short)h;
        pl[j] = (short)f2bf(rem);
      }
      *(short8*)&AsH[row][skc] = ph;
      *(short8*)&AsL[row][skc] = pl;
    }
#pragma unroll
    for (int p = 0; p < 2; ++p) {
      const int row = p * 64 + srow;
      const float* src = Bb + (size_t)row * K + kt + skc;
      const float4 v0 = *(const float4*)(src);
      const float4 v1 = *(const float4*)(src + 4);
      const float v[8] = {v0.x, v0.y, v0.z, v0.w, v1.x, v1.y, v1.z, v1.w};
      short8 pq;
#pragma unroll
      for (int j = 0; j < 8; ++j) {
        const u32 b = __float_as_uint(v[j]);
        const u16 q = ((b << 1) == 0) ? (u16)0 : (u16)(0x3F80u | ((b >> 16) & 0x8000u));
        pq[j] = (short)q;
      }
      *(short8*)&Bs[row][skc] = pq;
    }
    __syncthreads();
    short8 ah[4], al[4], bqf[4];
#pragma unroll
    for (int m = 0; m < 4; ++m) {
      ah[m] = *(const short8*)&AsH[wr * 64 + m * 16 + r0][k0];
      al[m] = *(const short8*)&AsL[wr * 64 + m * 16 + r0][k0];
    }
#pragma unroll
    for (int n = 0; n < 4; ++n)
      bqf[n] = *(const short8*)&Bs[wc * 64 + n * 16 + r0][k0];
#pragma unroll
    for (int m = 0; m < 4; ++m)
#pragma unroll
      for (int n = 0; n < 4; ++n) {
        acc[m][n] = __builtin_amdgcn_mfma_f32_16x16x32_bf16(ah[m], bqf[n], acc[m][n], 0, 0, 0);
        acc[m][n] = __builtin_amdgcn_mfma_f32_16x16x32_bf16(al[m], bqf[n], acc[m][n], 0, 0, 0);
      }
  }
  const int rbase = (lane >> 4) * 4;
  const int crow0 = brow * BM + wr * 64;
  const int ccol0 = bcol * BN + wc * 64;
#pragma unroll
  for (int n = 0; n < 4; ++n) {
    const int col = ccol0 + n * 16 + r0;
    const float bbv = Bias[col];
#pragma unroll
    for (int m = 0; m < 4; ++m) {
      const int row = crow0 + m * 16 + rbase;
#pragma unroll
      for (int j = 0; j < 4; ++j) {
        C[(size_t)(row + j) * N + col] = acc[m][n][j] + bbv;
      }
    }
  }
}

extern "C" void kernel_launch(void* const* d_in, const int* in_sizes, int n_in,
                              void* d_out, int out_size, void* d_ws, size_t ws_size,
                              hipStream_t stream) {
  const float* X = (const float*)d_in[0];     // [M, K] fp32
  const float* W = (const float*)d_in[1];     // [N, K] fp32
  const float* Bias = (const float*)d_in[2];  // [N] fp32
  float* C = (float*)d_out;                   // [M, N] fp32

  const int N = in_sizes[2];
  const int K = in_sizes[1] / N;
  const int M = in_sizes[0] / K;

  const size_t a_bytes = (size_t)M * K;  // i8 each term
  const size_t qw_bytes = (size_t)N * K;

  if (M == 8192 && N == 4096 && K == 4096 && ws_size >= 2 * a_bytes + qw_bytes) {
    char* A1 = (char*)d_ws;
    char* A2 = A1 + a_bytes;
    char* Qw = A2 + a_bytes;
    prep_x_i8<<<(M * K) / (4 * 256), 256, 0, stream>>>(X, A1, A2);
    prep_w_i8<<<(N * K) / (4 * 256), 256, 0, stream>>>(W, Qw);
    const int grid = (M / 256) * (N / 256);  // 512
    gemm256_i8<0><<<grid, 512, 0, stream>>>(A1, Qw, Bias, C);
    gemm256_i8<1><<<grid, 512, 0, stream>>>(A2, Qw, Bias, C);
  } else {
    bitnet_gemm_fallback<<<(M / BM) * (N / BN), 256, 0, stream>>>(X, W, Bias, C, M, N, K);
  }
}